// Round 3
// baseline (1515.041 us; speedup 1.0000x reference)
//
#include <hip/hip_runtime.h>
#include <hip/hip_bf16.h>

// MLP 4096x2048 -> [4096,4096,4096,1024], fp32 in/out.
// Strategy: bf16x3 split GEMM (a = a_hi + a_lo bf16; A*W ~= Ah*Wh + Ah*Wl + Al*Wh)
// on MFMA 16x16x32_bf16, fp32 accumulate. 128x128 tile, BK=32 (32KB LDS -> 3
// blocks/CU, avoids m132's 64KB occupancy cliff), global_load_lds(16B) staging,
// XOR-swizzled LDS reads (slot ^= (row>>1)&3, involution both sides),
// XCD-aware bijective block swizzle.

typedef __attribute__((ext_vector_type(4))) float f32x4;
typedef __attribute__((ext_vector_type(8))) short bf16x8;
typedef __attribute__((ext_vector_type(4))) unsigned short us4;

#define LDS_AS __attribute__((address_space(3)))
#define GLB_AS __attribute__((address_space(1)))

static __device__ __forceinline__ unsigned short f2bf(float f) {
    union { float f; unsigned int u; } x; x.f = f;
    // round-to-nearest-even bf16 (inputs finite; no NaN handling needed)
    unsigned int r = (x.u + 0x7FFFu + ((x.u >> 16) & 1u)) >> 16;
    return (unsigned short)r;
}
static __device__ __forceinline__ float bf2f(unsigned short u) {
    union { float f; unsigned int u; } x; x.u = ((unsigned int)u) << 16;
    return x.f;
}

// ---------------- fp32 -> (bf16 hi, bf16 lo) split ----------------
__global__ void split_kernel(const float* __restrict__ src,
                             unsigned short* __restrict__ hi,
                             unsigned short* __restrict__ lo, int n4) {
    int i = blockIdx.x * 256 + threadIdx.x;
    if (i >= n4) return;
    f32x4 v = ((const f32x4*)src)[i];
    us4 h, l;
#pragma unroll
    for (int j = 0; j < 4; ++j) {
        unsigned short hb = f2bf(v[j]);
        h[j] = hb;
        l[j] = f2bf(v[j] - bf2f(hb));
    }
    ((us4*)hi)[i] = h;
    ((us4*)lo)[i] = l;
}

// ---------------- split-bf16 GEMM: C = A @ W^T + b ----------------
// A: [M][K] as (Ahi,Alo) bf16. W: [N][K] as (Whi,Wlo) bf16 (row-major along K).
// SPLIT_OUT=1: write relu(C) as (Chi,Clo) bf16 pair. SPLIT_OUT=0: write fp32 Cf.
template <int RELU, int SPLIT_OUT>
__global__ __launch_bounds__(256, 3) void gemm_split(
    const unsigned short* __restrict__ Ahi, const unsigned short* __restrict__ Alo,
    const unsigned short* __restrict__ Whi, const unsigned short* __restrict__ Wlo,
    const float* __restrict__ bias,
    float* __restrict__ Cf,
    unsigned short* __restrict__ Chi, unsigned short* __restrict__ Clo,
    int M, int N, int K) {
    // 4 tiles [128][32] bf16 = 8KB each, 32KB total (single-buffered 2-barrier loop)
    __shared__ __align__(16) unsigned short sAhi[128 * 32];
    __shared__ __align__(16) unsigned short sAlo[128 * 32];
    __shared__ __align__(16) unsigned short sWhi[128 * 32];
    __shared__ __align__(16) unsigned short sWlo[128 * 32];

    const int tid = threadIdx.x;
    const int lane = tid & 63;
    const int wave = tid >> 6;
    const int wr = wave >> 1, wc = wave & 1;   // 2x2 waves, 64x64 out each

    // XCD-aware bijective block swizzle (grid % 8 == 0 for all our shapes)
    const int nbn = N >> 7;
    int wg = blockIdx.x;
    const int cpx = gridDim.x >> 3;
    wg = (wg & 7) * cpx + (wg >> 3);
    const int bm = (wg / nbn) << 7;
    const int bn = (wg % nbn) << 7;

    f32x4 acc[4][4];
#pragma unroll
    for (int i = 0; i < 4; ++i)
#pragma unroll
        for (int j = 0; j < 4; ++j) acc[i][j] = (f32x4){0.f, 0.f, 0.f, 0.f};

    const int r15 = lane & 15;
    const int kb = lane >> 4;  // 0..3 : 16B K-slot within the 32-K window

    const int nkt = K >> 5;
    for (int kt = 0; kt < nkt; ++kt) {
        const int k0 = kt << 5;
        __syncthreads();  // waves done reading previous tile
        // stage 4 tiles; LDS dest linear (wave-uniform base + lane*16);
        // global source pre-swizzled: slot (row,kc) receives data (row, kc^((row>>1)&3))
#pragma unroll
        for (int it = 0; it < 2; ++it) {
            const int c = it * 256 + wave * 64 + lane;  // chunk id, 0..511
            const int row = c >> 2;                     // 4 x 16B chunks per 64B row
            const int kc = c & 3;
            const int kcs = kc ^ ((row >> 1) & 3);
            const int lbase = (it * 256 + wave * 64) * 8;  // ushort idx, wave-uniform
            const size_t ga = (size_t)(bm + row) * K + k0 + kcs * 8;
            const size_t gw = (size_t)(bn + row) * K + k0 + kcs * 8;
            __builtin_amdgcn_global_load_lds((const GLB_AS void*)(Ahi + ga),
                                             (LDS_AS void*)(sAhi + lbase), 16, 0, 0);
            __builtin_amdgcn_global_load_lds((const GLB_AS void*)(Alo + ga),
                                             (LDS_AS void*)(sAlo + lbase), 16, 0, 0);
            __builtin_amdgcn_global_load_lds((const GLB_AS void*)(Whi + gw),
                                             (LDS_AS void*)(sWhi + lbase), 16, 0, 0);
            __builtin_amdgcn_global_load_lds((const GLB_AS void*)(Wlo + gw),
                                             (LDS_AS void*)(sWlo + lbase), 16, 0, 0);
        }
        __syncthreads();  // compiler drains vmcnt before barrier

        bf16x8 ah[4], al[4];
#pragma unroll
        for (int i = 0; i < 4; ++i) {
            const int row = wr * 64 + i * 16 + r15;
            const int us = kb ^ ((row >> 1) & 3);  // XOR-swizzled read (involution)
            ah[i] = *(const bf16x8*)&sAhi[row * 32 + us * 8];
            al[i] = *(const bf16x8*)&sAlo[row * 32 + us * 8];
        }
#pragma unroll
        for (int j = 0; j < 4; ++j) {
            const int row = wc * 64 + j * 16 + r15;
            const int us = kb ^ ((row >> 1) & 3);
            bf16x8 wh = *(const bf16x8*)&sWhi[row * 32 + us * 8];
            bf16x8 wl = *(const bf16x8*)&sWlo[row * 32 + us * 8];
#pragma unroll
            for (int i = 0; i < 4; ++i) {
                acc[i][j] = __builtin_amdgcn_mfma_f32_16x16x32_bf16(ah[i], wh, acc[i][j], 0, 0, 0);
                acc[i][j] = __builtin_amdgcn_mfma_f32_16x16x32_bf16(ah[i], wl, acc[i][j], 0, 0, 0);
                acc[i][j] = __builtin_amdgcn_mfma_f32_16x16x32_bf16(al[i], wh, acc[i][j], 0, 0, 0);
            }
        }
    }

    // epilogue: bias + optional relu; C/D layout: col=lane&15, row=(lane>>4)*4+reg
    float bv[4];
#pragma unroll
    for (int j = 0; j < 4; ++j) bv[j] = bias[bn + wc * 64 + j * 16 + r15];
#pragma unroll
    for (int i = 0; i < 4; ++i) {
#pragma unroll
        for (int j = 0; j < 4; ++j) {
            const int colg = bn + wc * 64 + j * 16 + r15;
#pragma unroll
            for (int r = 0; r < 4; ++r) {
                const int rowg = bm + wr * 64 + i * 16 + kb * 4 + r;
                float v = acc[i][j][r] + bv[j];
                if (RELU) v = v > 0.f ? v : 0.f;
                if constexpr (SPLIT_OUT) {
                    unsigned short h = f2bf(v);
                    Chi[(size_t)rowg * N + colg] = h;
                    Clo[(size_t)rowg * N + colg] = f2bf(v - bf2f(h));
                } else {
                    Cf[(size_t)rowg * N + colg] = v;
                }
            }
        }
    }
}

extern "C" void kernel_launch(void* const* d_in, const int* in_sizes, int n_in,
                              void* d_out, int out_size, void* d_ws, size_t ws_size,
                              hipStream_t stream) {
    const float* x  = (const float*)d_in[0];
    const float* W0 = (const float*)d_in[1];
    const float* b0 = (const float*)d_in[2];
    const float* W1 = (const float*)d_in[3];
    const float* b1 = (const float*)d_in[4];
    const float* W2 = (const float*)d_in[5];
    const float* b2 = (const float*)d_in[6];
    const float* W3 = (const float*)d_in[7];
    const float* b3 = (const float*)d_in[8];

    const int M = 4096;
    const int K0 = 2048;
    const int D0 = 4096, D1 = 4096, D2 = 4096, D3 = 1024;

    // workspace layout (all bf16/ushort): ~235 MB total
    unsigned short* p = (unsigned short*)d_ws;
    unsigned short* xhi = p; p += (size_t)M * K0;
    unsigned short* xlo = p; p += (size_t)M * K0;
    unsigned short* whi = p; p += (size_t)D1 * D0;  // reused for every layer's W
    unsigned short* wlo = p; p += (size_t)D1 * D0;
    unsigned short* h0hi = p; p += (size_t)M * D0;
    unsigned short* h0lo = p; p += (size_t)M * D0;
    unsigned short* h1hi = p; p += (size_t)M * D1;
    unsigned short* h1lo = p; p += (size_t)M * D1;

    auto split = [&](const float* src, unsigned short* hi, unsigned short* lo, size_t n) {
        int n4 = (int)(n >> 2);
        split_kernel<<<(n4 + 255) / 256, 256, 0, stream>>>(src, hi, lo, n4);
    };

    // L0: h0 = relu(x @ W0^T + b0)   [4096 x 4096, K=2048]
    split(x, xhi, xlo, (size_t)M * K0);
    split(W0, whi, wlo, (size_t)D0 * K0);
    gemm_split<1, 1><<<(M / 128) * (D0 / 128), 256, 0, stream>>>(
        xhi, xlo, whi, wlo, b0, nullptr, h0hi, h0lo, M, D0, K0);

    // L1: h1 = relu(h0 @ W1^T + b1)  [4096 x 4096, K=4096]
    split(W1, whi, wlo, (size_t)D1 * D0);
    gemm_split<1, 1><<<(M / 128) * (D1 / 128), 256, 0, stream>>>(
        h0hi, h0lo, whi, wlo, b1, nullptr, h1hi, h1lo, M, D1, D0);

    // L2: h2 = relu(h1 @ W2^T + b2)  [4096 x 4096, K=4096]
    split(W2, whi, wlo, (size_t)D2 * D1);
    gemm_split<1, 1><<<(M / 128) * (D2 / 128), 256, 0, stream>>>(
        h1hi, h1lo, whi, wlo, b2, nullptr, h0hi, h0lo, M, D2, D1);

    // L3: out = h2 @ W3^T + b3       [4096 x 1024, K=4096], fp32 out, no relu
    split(W3, whi, wlo, (size_t)D3 * D2);
    gemm_split<0, 0><<<(M / 128) * (D3 / 128), 256, 0, stream>>>(
        h0hi, h0lo, whi, wlo, b3, (float*)d_out, nullptr, nullptr, M, D3, D2);
}

// Round 5
// 1095.588 us; speedup vs baseline: 1.3829x; 1.3829x over previous
//
#include <hip/hip_runtime.h>
#include <hip/hip_bf16.h>

// MLP 4096x2048 -> [4096,4096,4096,1024], fp32 in/out.
// bf16x3 split GEMM (A*W ~= Ah*Wh + Ah*Wl + Al*Wh) on mfma_f32_16x16x32_bf16.
// L0-L2: 256x256 tile, BK=32, 8 waves, 4-phase schedule with counted vmcnt
// double-buffering (T3+T4), setprio (T5), XOR LDS swizzle (T2, measured 0
// conflicts in r3), XCD block swizzle (T1). 128KiB dynamic LDS.
// L3: proven 128x128 2-barrier kernel (N=1024 -> only 64 blocks at 256^2).

typedef __attribute__((ext_vector_type(4))) float f32x4;
typedef __attribute__((ext_vector_type(8))) short bf16x8;
typedef __attribute__((ext_vector_type(4))) unsigned short us4;

#define LDS_AS __attribute__((address_space(3)))
#define GLB_AS __attribute__((address_space(1)))

static __device__ __forceinline__ unsigned short f2bf(float f) {
    union { float f; unsigned int u; } x; x.f = f;
    unsigned int r = (x.u + 0x7FFFu + ((x.u >> 16) & 1u)) >> 16;  // RNE
    return (unsigned short)r;
}
static __device__ __forceinline__ float bf2f(unsigned short u) {
    union { float f; unsigned int u; } x; x.u = ((unsigned int)u) << 16;
    return x.f;
}

// ---------------- fp32 -> (bf16 hi, bf16 lo) split ----------------
__global__ void split_kernel(const float* __restrict__ src,
                             unsigned short* __restrict__ hi,
                             unsigned short* __restrict__ lo, int n4) {
    int i = blockIdx.x * 256 + threadIdx.x;
    if (i >= n4) return;
    f32x4 v = ((const f32x4*)src)[i];
    us4 h, l;
#pragma unroll
    for (int j = 0; j < 4; ++j) {
        unsigned short hb = f2bf(v[j]);
        h[j] = hb;
        l[j] = f2bf(v[j] - bf2f(hb));
    }
    ((us4*)hi)[i] = h;
    ((us4*)lo)[i] = l;
}

// ================= 256x256 4-phase split GEMM (L0-L2) =================
// LDS: buffer b (b=0,1) at b*32768 ushorts; tiles: 0=Ahi 1=Alo 2=Whi 3=Wlo,
// each [256][32] ushort (8192). Swizzle: slot s of row holds K-chunk s^((row>>1)&3).
template <int RELU, int SPLIT_OUT>
__global__ __launch_bounds__(512, 2) void gemm256(
    const unsigned short* __restrict__ Ahi, const unsigned short* __restrict__ Alo,
    const unsigned short* __restrict__ Whi, const unsigned short* __restrict__ Wlo,
    const float* __restrict__ bias,
    float* __restrict__ Cf,
    unsigned short* __restrict__ Chi, unsigned short* __restrict__ Clo,
    int M, int N, int K) {
    extern __shared__ unsigned short lds[];

    const int tid = threadIdx.x;
    const int lane = tid & 63;
    const int wave = tid >> 6;
    const int wr = wave >> 2;   // 0..1 : 128-row block
    const int wc = wave & 3;    // 0..3 : 64-col block
    const int r15 = lane & 15;
    const int kb = lane >> 4;   // 0..3 : 16B K-slot

    // XCD-aware bijective block swizzle (grid=256, %8==0)
    const int nbn = N >> 8;
    int wg = blockIdx.x;
    const int cpx = gridDim.x >> 3;
    wg = (wg & 7) * cpx + (wg >> 3);
    const int bm = (wg / nbn) << 8;
    const int bn = (wg % nbn) << 8;

    // staging map: 2 chunks/thread/tile; chunk c -> row c>>2, slot c&3,
    // source K-chunk (c&3)^((row>>1)&3); LDS dest linear at c*16B.
    const int r0 = tid >> 2;
    const int s0 = (tid & 3) ^ ((r0 >> 1) & 3);
    const int c1 = tid + 512;
    const int r1 = c1 >> 2;
    const int s1 = (c1 & 3) ^ ((r1 >> 1) & 3);

    f32x4 acc[8][4];
#pragma unroll
    for (int i = 0; i < 8; ++i)
#pragma unroll
        for (int j = 0; j < 4; ++j) acc[i][j] = (f32x4){0.f, 0.f, 0.f, 0.f};

    const int nkt = K >> 5;  // >= 64 for our shapes

    auto issue = [&](const unsigned short* __restrict__ G, int R0, int k0,
                     int buf, int tile) {
        unsigned short* dst = lds + buf * 32768 + tile * 8192;
        __builtin_amdgcn_global_load_lds(
            (const GLB_AS void*)(G + (size_t)(R0 + r0) * K + k0 + s0 * 8),
            (LDS_AS void*)(dst + tid * 8), 16, 0, 0);
        __builtin_amdgcn_global_load_lds(
            (const GLB_AS void*)(G + (size_t)(R0 + r1) * K + k0 + s1 * 8),
            (LDS_AS void*)(dst + c1 * 8), 16, 0, 0);
    };

    // prologue: t=0 all 4 tiles (8 loads) + t=1 A tiles (4 loads);
    // vmcnt(4) => t=0 landed, t=1's A still in flight.
    issue(Ahi, bm, 0, 0, 0);
    issue(Alo, bm, 0, 0, 1);
    issue(Whi, bn, 0, 0, 2);
    issue(Wlo, bn, 0, 0, 3);
    issue(Ahi, bm, 32, 1, 0);
    issue(Alo, bm, 32, 1, 1);
    asm volatile("s_waitcnt vmcnt(4)" ::: "memory");
    __builtin_amdgcn_s_barrier();
    asm volatile("" ::: "memory");

    bf16x8 a_[4][2], w_[4][2];

    for (int t = 0; t < nkt; ++t) {
        const int cur = t & 1, nxt = cur ^ 1;
        const unsigned short* base = lds + cur * 32768;
        const int k1 = (t + 1) << 5;

        // ---- P1: read A rows 0-3 + W cols 0-1; issue Whi(t+1) ----
#pragma unroll
        for (int i = 0; i < 4; ++i) {
            const int row = wr * 128 + i * 16 + r15;
            const int us = kb ^ ((row >> 1) & 3);
            a_[i][0] = *(const bf16x8*)(base + 0 * 8192 + row * 32 + us * 8);
            a_[i][1] = *(const bf16x8*)(base + 1 * 8192 + row * 32 + us * 8);
        }
#pragma unroll
        for (int j = 0; j < 2; ++j) {
            const int row = wc * 64 + j * 16 + r15;
            const int us = kb ^ ((row >> 1) & 3);
            w_[j][0] = *(const bf16x8*)(base + 2 * 8192 + row * 32 + us * 8);
            w_[j][1] = *(const bf16x8*)(base + 3 * 8192 + row * 32 + us * 8);
        }
        if (t + 1 < nkt) issue(Whi, bn, k1, nxt, 2);
        __builtin_amdgcn_s_barrier();
        __builtin_amdgcn_s_setprio(1);
#pragma unroll
        for (int j = 0; j < 2; ++j)
#pragma unroll
            for (int i = 0; i < 4; ++i) {
                acc[i][j] = __builtin_amdgcn_mfma_f32_16x16x32_bf16(a_[i][0], w_[j][0], acc[i][j], 0, 0, 0);
                acc[i][j] = __builtin_amdgcn_mfma_f32_16x16x32_bf16(a_[i][0], w_[j][1], acc[i][j], 0, 0, 0);
                acc[i][j] = __builtin_amdgcn_mfma_f32_16x16x32_bf16(a_[i][1], w_[j][0], acc[i][j], 0, 0, 0);
            }
        __builtin_amdgcn_s_setprio(0);
        __builtin_amdgcn_s_barrier();

        // ---- P2: read W cols 2-3; issue Wlo(t+1) ----
#pragma unroll
        for (int j = 2; j < 4; ++j) {
            const int row = wc * 64 + j * 16 + r15;
            const int us = kb ^ ((row >> 1) & 3);
            w_[j][0] = *(const bf16x8*)(base + 2 * 8192 + row * 32 + us * 8);
            w_[j][1] = *(const bf16x8*)(base + 3 * 8192 + row * 32 + us * 8);
        }
        if (t + 1 < nkt) issue(Wlo, bn, k1, nxt, 3);
        __builtin_amdgcn_s_barrier();
        __builtin_amdgcn_s_setprio(1);
#pragma unroll
        for (int j = 2; j < 4; ++j)
#pragma unroll
            for (int i = 0; i < 4; ++i) {
                acc[i][j] = __builtin_amdgcn_mfma_f32_16x16x32_bf16(a_[i][0], w_[j][0], acc[i][j], 0, 0, 0);
                acc[i][j] = __builtin_amdgcn_mfma_f32_16x16x32_bf16(a_[i][0], w_[j][1], acc[i][j], 0, 0, 0);
                acc[i][j] = __builtin_amdgcn_mfma_f32_16x16x32_bf16(a_[i][1], w_[j][0], acc[i][j], 0, 0, 0);
            }
        __builtin_amdgcn_s_setprio(0);
        __builtin_amdgcn_s_barrier();

        // ---- P3: read A rows 4-7 (last reads of buf[cur]) ----
#pragma unroll
        for (int i = 0; i < 4; ++i) {
            const int row = wr * 128 + (4 + i) * 16 + r15;
            const int us = kb ^ ((row >> 1) & 3);
            a_[i][0] = *(const bf16x8*)(base + 0 * 8192 + row * 32 + us * 8);
            a_[i][1] = *(const bf16x8*)(base + 1 * 8192 + row * 32 + us * 8);
        }
        __builtin_amdgcn_s_barrier();
        __builtin_amdgcn_s_setprio(1);
#pragma unroll
        for (int j = 0; j < 2; ++j)
#pragma unroll
            for (int i = 0; i < 4; ++i) {
                acc[4 + i][j] = __builtin_amdgcn_mfma_f32_16x16x32_bf16(a_[i][0], w_[j][0], acc[4 + i][j], 0, 0, 0);
                acc[4 + i][j] = __builtin_amdgcn_mfma_f32_16x16x32_bf16(a_[i][0], w_[j][1], acc[4 + i][j], 0, 0, 0);
                acc[4 + i][j] = __builtin_amdgcn_mfma_f32_16x16x32_bf16(a_[i][1], w_[j][0], acc[4 + i][j], 0, 0, 0);
            }
        __builtin_amdgcn_s_setprio(0);
        __builtin_amdgcn_s_barrier();  // end-read fence: buf[cur] free for t+2

        // ---- P4: issue A(t+2) into buf[cur]; MFMA last quadrant ----
        if (t + 2 < nkt) {
            const int k2 = (t + 2) << 5;
            issue(Ahi, bm, k2, cur, 0);
            issue(Alo, bm, k2, cur, 1);
        }
        __builtin_amdgcn_s_setprio(1);
#pragma unroll
        for (int j = 2; j < 4; ++j)
#pragma unroll
            for (int i = 0; i < 4; ++i) {
                acc[4 + i][j] = __builtin_amdgcn_mfma_f32_16x16x32_bf16(a_[i][0], w_[j][0], acc[4 + i][j], 0, 0, 0);
                acc[4 + i][j] = __builtin_amdgcn_mfma_f32_16x16x32_bf16(a_[i][0], w_[j][1], acc[4 + i][j], 0, 0, 0);
                acc[4 + i][j] = __builtin_amdgcn_mfma_f32_16x16x32_bf16(a_[i][1], w_[j][0], acc[4 + i][j], 0, 0, 0);
            }
        __builtin_amdgcn_s_setprio(0);

        // ---- boundary: counted wait (never 0 mid-loop), landed fence ----
        if (t + 1 < nkt) {
            if (t + 2 < nkt) asm volatile("s_waitcnt vmcnt(4)" ::: "memory");
            else             asm volatile("s_waitcnt vmcnt(0)" ::: "memory");
        }
        __builtin_amdgcn_s_barrier();
        asm volatile("" ::: "memory");
    }

    // epilogue: bias + optional relu; C/D map: col=lane&15, row=(lane>>4)*4+reg
    float bv[4];
#pragma unroll
    for (int j = 0; j < 4; ++j) bv[j] = bias[bn + wc * 64 + j * 16 + r15];
#pragma unroll
    for (int i = 0; i < 8; ++i) {
#pragma unroll
        for (int j = 0; j < 4; ++j) {
            const int colg = bn + wc * 64 + j * 16 + r15;
#pragma unroll
            for (int r = 0; r < 4; ++r) {
                const int rowg = bm + wr * 128 + i * 16 + kb * 4 + r;
                float v = acc[i][j][r] + bv[j];
                if (RELU) v = v > 0.f ? v : 0.f;
                if constexpr (SPLIT_OUT) {
                    unsigned short h = f2bf(v);
                    Chi[(size_t)rowg * N + colg] = h;
                    Clo[(size_t)rowg * N + colg] = f2bf(v - bf2f(h));
                } else {
                    Cf[(size_t)rowg * N + colg] = v;
                }
            }
        }
    }
}

// ================= 128x128 2-barrier split GEMM (L3) =================
template <int RELU, int SPLIT_OUT>
__global__ __launch_bounds__(256, 3) void gemm_split(
    const unsigned short* __restrict__ Ahi, const unsigned short* __restrict__ Alo,
    const unsigned short* __restrict__ Whi, const unsigned short* __restrict__ Wlo,
    const float* __restrict__ bias,
    float* __restrict__ Cf,
    unsigned short* __restrict__ Chi, unsigned short* __restrict__ Clo,
    int M, int N, int K) {
    __shared__ __align__(16) unsigned short sAhi[128 * 32];
    __shared__ __align__(16) unsigned short sAlo[128 * 32];
    __shared__ __align__(16) unsigned short sWhi[128 * 32];
    __shared__ __align__(16) unsigned short sWlo[128 * 32];

    const int tid = threadIdx.x;
    const int lane = tid & 63;
    const int wave = tid >> 6;
    const int wr = wave >> 1, wc = wave & 1;

    const int nbn = N >> 7;
    int wg = blockIdx.x;
    const int cpx = gridDim.x >> 3;
    wg = (wg & 7) * cpx + (wg >> 3);
    const int bm = (wg / nbn) << 7;
    const int bn = (wg % nbn) << 7;

    f32x4 acc[4][4];
#pragma unroll
    for (int i = 0; i < 4; ++i)
#pragma unroll
        for (int j = 0; j < 4; ++j) acc[i][j] = (f32x4){0.f, 0.f, 0.f, 0.f};

    const int r15 = lane & 15;
    const int kb = lane >> 4;

    const int nkt = K >> 5;
    for (int kt = 0; kt < nkt; ++kt) {
        const int k0 = kt << 5;
        __syncthreads();
#pragma unroll
        for (int it = 0; it < 2; ++it) {
            const int c = it * 256 + wave * 64 + lane;
            const int row = c >> 2;
            const int kcs = (c & 3) ^ ((row >> 1) & 3);
            const int lbase = (it * 256 + wave * 64) * 8;
            const size_t ga = (size_t)(bm + row) * K + k0 + kcs * 8;
            const size_t gw = (size_t)(bn + row) * K + k0 + kcs * 8;
            __builtin_amdgcn_global_load_lds((const GLB_AS void*)(Ahi + ga),
                                             (LDS_AS void*)(sAhi + lbase), 16, 0, 0);
            __builtin_amdgcn_global_load_lds((const GLB_AS void*)(Alo + ga),
                                             (LDS_AS void*)(sAlo + lbase), 16, 0, 0);
            __builtin_amdgcn_global_load_lds((const GLB_AS void*)(Whi + gw),
                                             (LDS_AS void*)(sWhi + lbase), 16, 0, 0);
            __builtin_amdgcn_global_load_lds((const GLB_AS void*)(Wlo + gw),
                                             (LDS_AS void*)(sWlo + lbase), 16, 0, 0);
        }
        __syncthreads();

        bf16x8 ah[4], al[4];
#pragma unroll
        for (int i = 0; i < 4; ++i) {
            const int row = wr * 64 + i * 16 + r15;
            const int us = kb ^ ((row >> 1) & 3);
            ah[i] = *(const bf16x8*)&sAhi[row * 32 + us * 8];
            al[i] = *(const bf16x8*)&sAlo[row * 32 + us * 8];
        }
#pragma unroll
        for (int j = 0; j < 4; ++j) {
            const int row = wc * 64 + j * 16 + r15;
            const int us = kb ^ ((row >> 1) & 3);
            bf16x8 wh = *(const bf16x8*)&sWhi[row * 32 + us * 8];
            bf16x8 wl = *(const bf16x8*)&sWlo[row * 32 + us * 8];
#pragma unroll
            for (int i = 0; i < 4; ++i) {
                acc[i][j] = __builtin_amdgcn_mfma_f32_16x16x32_bf16(ah[i], wh, acc[i][j], 0, 0, 0);
                acc[i][j] = __builtin_amdgcn_mfma_f32_16x16x32_bf16(ah[i], wl, acc[i][j], 0, 0, 0);
                acc[i][j] = __builtin_amdgcn_mfma_f32_16x16x32_bf16(al[i], wh, acc[i][j], 0, 0, 0);
            }
        }
    }

    float bv[4];
#pragma unroll
    for (int j = 0; j < 4; ++j) bv[j] = bias[bn + wc * 64 + j * 16 + r15];
#pragma unroll
    for (int i = 0; i < 4; ++i) {
#pragma unroll
        for (int j = 0; j < 4; ++j) {
            const int colg = bn + wc * 64 + j * 16 + r15;
#pragma unroll
            for (int r = 0; r < 4; ++r) {
                const int rowg = bm + wr * 64 + i * 16 + kb * 4 + r;
                float v = acc[i][j][r] + bv[j];
                if (RELU) v = v > 0.f ? v : 0.f;
                if constexpr (SPLIT_OUT) {
                    unsigned short h = f2bf(v);
                    Chi[(size_t)rowg * N + colg] = h;
                    Clo[(size_t)rowg * N + colg] = f2bf(v - bf2f(h));
                } else {
                    Cf[(size_t)rowg * N + colg] = v;
                }
            }
        }
    }
}

extern "C" void kernel_launch(void* const* d_in, const int* in_sizes, int n_in,
                              void* d_out, int out_size, void* d_ws, size_t ws_size,
                              hipStream_t stream) {
    const float* x  = (const float*)d_in[0];
    const float* W0 = (const float*)d_in[1];
    const float* b0 = (const float*)d_in[2];
    const float* W1 = (const float*)d_in[3];
    const float* b1 = (const float*)d_in[4];
    const float* W2 = (const float*)d_in[5];
    const float* b2 = (const float*)d_in[6];
    const float* W3 = (const float*)d_in[7];
    const float* b3 = (const float*)d_in[8];

    const int M = 4096;
    const int K0 = 2048;
    const int D0 = 4096, D1 = 4096, D2 = 4096, D3 = 1024;

    // allow 128 KiB dynamic LDS — unconditional every call (no static guards;
    // host-side attribute setter, not a stream op, so capture-safe & idempotent)
    hipFuncSetAttribute(reinterpret_cast<const void*>(&gemm256<1, 1>),
                        hipFuncAttributeMaxDynamicSharedMemorySize, 131072);

    unsigned short* p = (unsigned short*)d_ws;
    unsigned short* xhi = p; p += (size_t)M * K0;
    unsigned short* xlo = p; p += (size_t)M * K0;
    unsigned short* whi = p; p += (size_t)D1 * D0;
    unsigned short* wlo = p; p += (size_t)D1 * D0;
    unsigned short* h0hi = p; p += (size_t)M * D0;
    unsigned short* h0lo = p; p += (size_t)M * D0;
    unsigned short* h1hi = p; p += (size_t)M * D1;
    unsigned short* h1lo = p; p += (size_t)M * D1;

    auto split = [&](const float* src, unsigned short* hi, unsigned short* lo, size_t n) {
        int n4 = (int)(n >> 2);
        split_kernel<<<(n4 + 255) / 256, 256, 0, stream>>>(src, hi, lo, n4);
    };

    // L0: h0 = relu(x @ W0^T + b0)   [4096 x 4096, K=2048]
    split(x, xhi, xlo, (size_t)M * K0);
    split(W0, whi, wlo, (size_t)D0 * K0);
    gemm256<1, 1><<<(M / 256) * (D0 / 256), 512, 131072, stream>>>(
        xhi, xlo, whi, wlo, b0, nullptr, h0hi, h0lo, M, D0, K0);

    // L1: h1 = relu(h0 @ W1^T + b1)  [4096 x 4096, K=4096]
    split(W1, whi, wlo, (size_t)D1 * D0);
    gemm256<1, 1><<<(M / 256) * (D1 / 256), 512, 131072, stream>>>(
        h0hi, h0lo, whi, wlo, b1, nullptr, h1hi, h1lo, M, D1, D0);

    // L2: h2 = relu(h1 @ W2^T + b2)  [4096 x 4096, K=4096]
    split(W2, whi, wlo, (size_t)D2 * D1);
    gemm256<1, 1><<<(M / 256) * (D2 / 256), 512, 131072, stream>>>(
        h1hi, h1lo, whi, wlo, b2, nullptr, h0hi, h0lo, M, D2, D1);

    // L3: out = h2 @ W3^T + b3       [4096 x 1024, K=4096], fp32 out, no relu
    split(W3, whi, wlo, (size_t)D3 * D2);
    gemm_split<0, 0><<<(M / 128) * (D3 / 128), 256, 0, stream>>>(
        h0hi, h0lo, whi, wlo, b3, (float*)d_out, nullptr, nullptr, M, D3, D2);
}

// Round 7
// 1048.439 us; speedup vs baseline: 1.4450x; 1.0450x over previous
//
#include <hip/hip_runtime.h>
#include <hip/hip_bf16.h>

// MLP 4096x2048 -> [4096,4096,4096,1024], fp32 in/out.
// bf16x3 split GEMM (A*W ~= Ah*Wh + Ah*Wl + Al*Wh) on mfma_f32_16x16x32_bf16.
// All layers: 256x256 tile, BK=32, 8 waves, 2-phase/tile schedule with counted
// vmcnt double-buffering (T3+T4), setprio (T5), XOR LDS swizzle (T2, measured 0
// conflicts), XCD block swizzle (T1). 128KiB dynamic LDS.
// L3 (N=1024): split-K=4 partials + reduce (keeps grid=256, 1 block/CU).

typedef __attribute__((ext_vector_type(4))) float f32x4;
typedef __attribute__((ext_vector_type(8))) short bf16x8;
typedef __attribute__((ext_vector_type(4))) unsigned short us4;

#define LDS_AS __attribute__((address_space(3)))
#define GLB_AS __attribute__((address_space(1)))

static __device__ __forceinline__ unsigned short f2bf(float f) {
    union { float f; unsigned int u; } x; x.f = f;
    unsigned int r = (x.u + 0x7FFFu + ((x.u >> 16) & 1u)) >> 16;  // RNE
    return (unsigned short)r;
}
static __device__ __forceinline__ float bf2f(unsigned short u) {
    union { float f; unsigned int u; } x; x.u = ((unsigned int)u) << 16;
    return x.f;
}

// ---------------- fp32 -> (bf16 hi, bf16 lo) split ----------------
__global__ void split_kernel(const float* __restrict__ src,
                             unsigned short* __restrict__ hi,
                             unsigned short* __restrict__ lo, int n4) {
    int i = blockIdx.x * 256 + threadIdx.x;
    if (i >= n4) return;
    f32x4 v = ((const f32x4*)src)[i];
    us4 h, l;
#pragma unroll
    for (int j = 0; j < 4; ++j) {
        unsigned short hb = f2bf(v[j]);
        h[j] = hb;
        l[j] = f2bf(v[j] - bf2f(hb));
    }
    ((us4*)hi)[i] = h;
    ((us4*)lo)[i] = l;
}

// ---------------- split-K reduce: out = sum(partials) + bias ----------------
__global__ void reduce4_bias(const float* __restrict__ part,
                             const float* __restrict__ bias,
                             float* __restrict__ out, int n4, int N, size_t stride) {
    int i = blockIdx.x * 256 + threadIdx.x;
    if (i >= n4) return;
    f32x4 v = ((const f32x4*)part)[i];
    v += ((const f32x4*)(part + stride))[i];
    v += ((const f32x4*)(part + 2 * stride))[i];
    v += ((const f32x4*)(part + 3 * stride))[i];
    f32x4 b = *(const f32x4*)&bias[(i * 4) & (N - 1)];
    ((f32x4*)out)[i] = v + b;
}

// ================= 256x256 2-phase split GEMM =================
// LDS: buffer b (b=0,1) at b*32768 ushorts; tiles: 0=Ahi 1=Alo 2=Whi 3=Wlo,
// each [256][32] ushort (8192). Swizzle: slot s of row holds K-chunk s^((row>>1)&3).
// Ks = row stride (full K), Kl = K elements processed per block.
// KSPLIT=4: wg decomposes to (tile, kchunk); A/W offset kc*Kl; Cf offset kc*M*N.
template <int RELU, int SPLIT_OUT, int BIAS, int KSPLIT>
__global__ __launch_bounds__(512, 2) void gemm256(
    const unsigned short* __restrict__ Ahi, const unsigned short* __restrict__ Alo,
    const unsigned short* __restrict__ Whi, const unsigned short* __restrict__ Wlo,
    const float* __restrict__ bias,
    float* __restrict__ Cf,
    unsigned short* __restrict__ Chi, unsigned short* __restrict__ Clo,
    int M, int N, int Ks, int Kl) {
    extern __shared__ unsigned short lds[];

    const int tid = threadIdx.x;
    const int lane = tid & 63;
    const int wave = tid >> 6;
    const int wr = wave >> 2;   // 0..1 : 128-row block
    const int wc = wave & 3;    // 0..3 : 64-col block
    const int r15 = lane & 15;
    const int kb = lane >> 4;   // 0..3 : 16B K-slot

    // XCD-aware bijective block swizzle (grid=256, %8==0)
    int wg = blockIdx.x;
    const int cpx = gridDim.x >> 3;
    wg = (wg & 7) * cpx + (wg >> 3);
    int kc = 0;
    if constexpr (KSPLIT == 4) { kc = wg & 3; wg >>= 2; }
    const int nbn = N >> 8;
    const int bm = (wg / nbn) << 8;
    const int bn = (wg % nbn) << 8;
    const int koff = kc * Kl;  // element offset along K for this block's chunk

    // staging map: 2 chunks/thread/tile; chunk c -> row c>>2, slot c&3,
    // source K-chunk (c&3)^((row>>1)&3); LDS dest linear at c*16B.
    const int r0 = tid >> 2;
    const int s0 = (tid & 3) ^ ((r0 >> 1) & 3);
    const int c1 = tid + 512;
    const int r1 = c1 >> 2;
    const int s1 = (c1 & 3) ^ ((r1 >> 1) & 3);

    f32x4 acc[8][4];
#pragma unroll
    for (int i = 0; i < 8; ++i)
#pragma unroll
        for (int j = 0; j < 4; ++j) acc[i][j] = (f32x4){0.f, 0.f, 0.f, 0.f};

    const int nkt = Kl >> 5;  // >= 32 for all our launches

    auto issue = [&](const unsigned short* __restrict__ G, int R0, int k0,
                     int buf, int tile) {
        unsigned short* dst = lds + buf * 32768 + tile * 8192;
        __builtin_amdgcn_global_load_lds(
            (const GLB_AS void*)(G + (size_t)(R0 + r0) * Ks + koff + k0 + s0 * 8),
            (LDS_AS void*)(dst + tid * 8), 16, 0, 0);
        __builtin_amdgcn_global_load_lds(
            (const GLB_AS void*)(G + (size_t)(R0 + r1) * Ks + koff + k0 + s1 * 8),
            (LDS_AS void*)(dst + c1 * 8), 16, 0, 0);
    };

    // prologue: t=0 all 4 tiles (8 loads) + t=1 A tiles (4 loads);
    // vmcnt(4) => t=0 landed (per-wave; barrier completes collective), t=1 A in flight.
    issue(Ahi, bm, 0, 0, 0);
    issue(Alo, bm, 0, 0, 1);
    issue(Whi, bn, 0, 0, 2);
    issue(Wlo, bn, 0, 0, 3);
    issue(Ahi, bm, 32, 1, 0);
    issue(Alo, bm, 32, 1, 1);
    asm volatile("s_waitcnt vmcnt(4)" ::: "memory");
    __builtin_amdgcn_s_barrier();
    asm volatile("" ::: "memory");

    bf16x8 a_[4][2], w_[4][2];

    for (int t = 0; t < nkt; ++t) {
        const int cur = t & 1, nxt = cur ^ 1;
        const unsigned short* base = lds + cur * 32768;
        const int k1 = (t + 1) << 5;

        // ======== Phase A: read A rows 0-3 + W cols 0-3; issue W(t+1) ========
#pragma unroll
        for (int i = 0; i < 4; ++i) {
            const int row = wr * 128 + i * 16 + r15;
            const int us = kb ^ ((row >> 1) & 3);
            a_[i][0] = *(const bf16x8*)(base + 0 * 8192 + row * 32 + us * 8);
            a_[i][1] = *(const bf16x8*)(base + 1 * 8192 + row * 32 + us * 8);
        }
#pragma unroll
        for (int j = 0; j < 4; ++j) {
            const int row = wc * 64 + j * 16 + r15;
            const int us = kb ^ ((row >> 1) & 3);
            w_[j][0] = *(const bf16x8*)(base + 2 * 8192 + row * 32 + us * 8);
            w_[j][1] = *(const bf16x8*)(base + 3 * 8192 + row * 32 + us * 8);
        }
        if (t + 1 < nkt) {
            issue(Whi, bn, k1, nxt, 2);
            issue(Wlo, bn, k1, nxt, 3);
        }
        __builtin_amdgcn_s_barrier();
        __builtin_amdgcn_s_setprio(1);
#pragma unroll
        for (int j = 0; j < 4; ++j)
#pragma unroll
            for (int i = 0; i < 4; ++i) {
                acc[i][j] = __builtin_amdgcn_mfma_f32_16x16x32_bf16(a_[i][0], w_[j][0], acc[i][j], 0, 0, 0);
                acc[i][j] = __builtin_amdgcn_mfma_f32_16x16x32_bf16(a_[i][0], w_[j][1], acc[i][j], 0, 0, 0);
                acc[i][j] = __builtin_amdgcn_mfma_f32_16x16x32_bf16(a_[i][1], w_[j][0], acc[i][j], 0, 0, 0);
            }
        __builtin_amdgcn_s_setprio(0);
        __builtin_amdgcn_s_barrier();

        // ======== Phase B: read A rows 4-7 (last reads of buf[cur]) ========
#pragma unroll
        for (int i = 0; i < 4; ++i) {
            const int row = wr * 128 + (4 + i) * 16 + r15;
            const int us = kb ^ ((row >> 1) & 3);
            a_[i][0] = *(const bf16x8*)(base + 0 * 8192 + row * 32 + us * 8);
            a_[i][1] = *(const bf16x8*)(base + 1 * 8192 + row * 32 + us * 8);
        }
        // reads complete in-VGPR before the fence barrier -> buf[cur] safely writable
        asm volatile("s_waitcnt lgkmcnt(0)" ::: "memory");
        __builtin_amdgcn_s_barrier();  // end-read fence
        if (t + 2 < nkt) {
            const int k2 = (t + 2) << 5;
            issue(Ahi, bm, k2, cur, 0);
            issue(Alo, bm, k2, cur, 1);
        }
        __builtin_amdgcn_s_setprio(1);
#pragma unroll
        for (int j = 0; j < 4; ++j)
#pragma unroll
            for (int i = 0; i < 4; ++i) {
                acc[4 + i][j] = __builtin_amdgcn_mfma_f32_16x16x32_bf16(a_[i][0], w_[j][0], acc[4 + i][j], 0, 0, 0);
                acc[4 + i][j] = __builtin_amdgcn_mfma_f32_16x16x32_bf16(a_[i][0], w_[j][1], acc[4 + i][j], 0, 0, 0);
                acc[4 + i][j] = __builtin_amdgcn_mfma_f32_16x16x32_bf16(a_[i][1], w_[j][0], acc[4 + i][j], 0, 0, 0);
            }
        __builtin_amdgcn_s_setprio(0);

        // ---- boundary: counted wait (never 0 mid-loop), collective fence ----
        if (t + 1 < nkt) {
            if (t + 2 < nkt) asm volatile("s_waitcnt vmcnt(4)" ::: "memory");
            else             asm volatile("s_waitcnt vmcnt(0)" ::: "memory");
        }
        __builtin_amdgcn_s_barrier();
        asm volatile("" ::: "memory");
    }

    // epilogue; C/D map: col=lane&15, row=(lane>>4)*4+reg
    if constexpr (KSPLIT == 4) Cf += (size_t)kc * ((size_t)M * N);
    float bv[4];
    if constexpr (BIAS) {
#pragma unroll
        for (int j = 0; j < 4; ++j) bv[j] = bias[bn + wc * 64 + j * 16 + r15];
    } else {
#pragma unroll
        for (int j = 0; j < 4; ++j) bv[j] = 0.f;
    }
#pragma unroll
    for (int i = 0; i < 8; ++i) {
#pragma unroll
        for (int j = 0; j < 4; ++j) {
            const int colg = bn + wc * 64 + j * 16 + r15;
#pragma unroll
            for (int r = 0; r < 4; ++r) {
                const int rowg = bm + wr * 128 + i * 16 + kb * 4 + r;
                float v = acc[i][j][r] + bv[j];
                if (RELU) v = v > 0.f ? v : 0.f;
                if constexpr (SPLIT_OUT) {
                    unsigned short h = f2bf(v);
                    Chi[(size_t)rowg * N + colg] = h;
                    Clo[(size_t)rowg * N + colg] = f2bf(v - bf2f(h));
                } else {
                    Cf[(size_t)rowg * N + colg] = v;
                }
            }
        }
    }
}

extern "C" void kernel_launch(void* const* d_in, const int* in_sizes, int n_in,
                              void* d_out, int out_size, void* d_ws, size_t ws_size,
                              hipStream_t stream) {
    const float* x  = (const float*)d_in[0];
    const float* W0 = (const float*)d_in[1];
    const float* b0 = (const float*)d_in[2];
    const float* W1 = (const float*)d_in[3];
    const float* b1 = (const float*)d_in[4];
    const float* W2 = (const float*)d_in[5];
    const float* b2 = (const float*)d_in[6];
    const float* W3 = (const float*)d_in[7];
    const float* b3 = (const float*)d_in[8];

    const int M = 4096;
    const int K0 = 2048;
    const int D0 = 4096, D1 = 4096, D2 = 4096, D3 = 1024;

    // allow 128 KiB dynamic LDS — unconditional (host-side, capture-safe, idempotent)
    hipFuncSetAttribute(reinterpret_cast<const void*>(&gemm256<1, 1, 1, 1>),
                        hipFuncAttributeMaxDynamicSharedMemorySize, 131072);
    hipFuncSetAttribute(reinterpret_cast<const void*>(&gemm256<0, 0, 0, 4>),
                        hipFuncAttributeMaxDynamicSharedMemorySize, 131072);

    unsigned short* p = (unsigned short*)d_ws;
    unsigned short* xhi = p; p += (size_t)M * K0;
    unsigned short* xlo = p; p += (size_t)M * K0;
    unsigned short* whi = p; p += (size_t)D1 * D0;
    unsigned short* wlo = p; p += (size_t)D1 * D0;
    unsigned short* h0hi = p; p += (size_t)M * D0;
    unsigned short* h0lo = p; p += (size_t)M * D0;
    unsigned short* h1hi = p; p += (size_t)M * D1;
    unsigned short* h1lo = p; p += (size_t)M * D1;
    // L3 split-K partials: reuse dead h1 region (4 x M x D3 f32 = 67MB = h1hi+h1lo)
    float* part = (float*)h1hi;

    auto split = [&](const float* src, unsigned short* hi, unsigned short* lo, size_t n) {
        int n4 = (int)(n >> 2);
        split_kernel<<<(n4 + 255) / 256, 256, 0, stream>>>(src, hi, lo, n4);
    };

    // L0: h0 = relu(x @ W0^T + b0)   [4096 x 4096, K=2048]
    split(x, xhi, xlo, (size_t)M * K0);
    split(W0, whi, wlo, (size_t)D0 * K0);
    gemm256<1, 1, 1, 1><<<(M / 256) * (D0 / 256), 512, 131072, stream>>>(
        xhi, xlo, whi, wlo, b0, nullptr, h0hi, h0lo, M, D0, K0, K0);

    // L1: h1 = relu(h0 @ W1^T + b1)  [4096 x 4096, K=4096]
    split(W1, whi, wlo, (size_t)D1 * D0);
    gemm256<1, 1, 1, 1><<<(M / 256) * (D1 / 256), 512, 131072, stream>>>(
        h0hi, h0lo, whi, wlo, b1, nullptr, h1hi, h1lo, M, D1, D0, D0);

    // L2: h2 = relu(h1 @ W2^T + b2)  [4096 x 4096, K=4096]
    split(W2, whi, wlo, (size_t)D2 * D1);
    gemm256<1, 1, 1, 1><<<(M / 256) * (D2 / 256), 512, 131072, stream>>>(
        h1hi, h1lo, whi, wlo, b2, nullptr, h0hi, h0lo, M, D2, D1, D1);

    // L3: out = h2 @ W3^T + b3       [4096 x 1024, K=4096], split-K=4, fp32 out
    split(W3, whi, wlo, (size_t)D3 * D2);
    gemm256<0, 0, 0, 4><<<(M / 256) * (D3 / 256) * 4, 512, 131072, stream>>>(
        h0hi, h0lo, whi, wlo, b3, part, nullptr, nullptr, M, D3, D2, D2 / 4);
    {
        int n4 = M * D3 / 4;
        reduce4_bias<<<(n4 + 255) / 256, 256, 0, stream>>>(
            part, b3, (float*)d_out, n4, D3, (size_t)M * D3);
    }
}